// Round 1
// baseline (170.857 us; speedup 1.0000x reference)
//
#include <hip/hip_runtime.h>
#include <cmath>

#define N_PTS 32768
#define HID   256
#define KTEST 1024
#define MB    32       // points per mlp block
#define RS    264      // padded H row stride (528 B = 33*16): keeps b128 rows 16B-aligned
#define SKC   256      // points per sk block
#define SKYB  (N_PTS / SKC)     // 128
#define SKGRID (4 * SKYB)       // 512 blocks total

typedef float  f32x4  __attribute__((ext_vector_type(4)));
typedef float  f32x16 __attribute__((ext_vector_type(16)));
typedef short  s16x4  __attribute__((ext_vector_type(4)));
typedef short  s16x8  __attribute__((ext_vector_type(8)));
typedef __bf16 bf16x8 __attribute__((ext_vector_type(8)));

__device__ __forceinline__ float b2f(unsigned short s) {
    return __uint_as_float(((unsigned int)s) << 16);
}
// native RNE fp32->bf16 (v_cvt_pk_bf16_f32 on gfx950); bit-identical to
// manual round-to-nearest-even, 1 instr instead of 3.
__device__ __forceinline__ unsigned short cvt16(float x) {
    return __builtin_bit_cast(unsigned short, (__bf16)x);
}
// exact split for W: x = hi + lo_f (exact), lo = RNE16(lo_f)
__device__ __forceinline__ void split2(float x, unsigned short& hi, unsigned short& lo) {
    unsigned int b = __float_as_uint(x);
    hi = (unsigned short)(b >> 16);
    float hf = __uint_as_float(b & 0xFFFF0000u);
    lo = cvt16(x - hf);
}
__device__ __forceinline__ float fast_tanh(float z) {
    float e = __expf(2.0f * z);
    return 1.0f - 2.0f / (e + 1.0f);
}

// ---------------------------------------------------------------------------
// W[k][n] fp32 -> hi/lo bf16 in 32x32x16 MFMA B-fragment order:
//   lane l (h=l>>5, c=l&31), reg j holds W[kc*32 + ks*16 + h*8 + j][t*32 + c]
//   elem offset = (((t*8 + kc)*2 + ks)*64 + l)*8
// (A and B use the same (h,j)->k mapping; any consistent bijective k-labeling
//  is contraction-invariant, and the C/D mapping used below is HW-verified.)
// Also zeroes the sk done-counter (stream-ordered before sk_loss).
// ---------------------------------------------------------------------------
__global__ __launch_bounds__(64) void wswz_kernel(
    const float* __restrict__ W1, const float* __restrict__ W2,
    unsigned short* __restrict__ Wh1, unsigned short* __restrict__ Wl1,
    unsigned short* __restrict__ Wh2, unsigned short* __restrict__ Wl2,
    unsigned int* __restrict__ counter)
{
    const int lane = threadIdx.x;      // 0..63
    const int t  = blockIdx.x;         // col tile 0..7 (32 cols each)
    const int kc = blockIdx.y;         // k chunk 0..7
    const float* W = blockIdx.z ? W2 : W1;
    unsigned short* Wh = blockIdx.z ? Wh2 : Wh1;
    unsigned short* Wl = blockIdx.z ? Wl2 : Wl1;
    const int h = lane >> 5, c = lane & 31;
    const int col = t * 32 + c;

    #pragma unroll
    for (int ks = 0; ks < 2; ++ks) {
        const int kb = kc * 32 + ks * 16 + h * 8;
        s16x8 hv, lv;
        #pragma unroll
        for (int j = 0; j < 8; ++j) {
            unsigned short hh, ll;
            split2(W[(kb + j) * HID + col], hh, ll);
            hv[j] = (short)hh; lv[j] = (short)ll;
        }
        const int out = (((t * 8 + kc) * 2 + ks) * 64 + lane) * 8;
        *(s16x8*)(Wh + out) = hv;
        *(s16x8*)(Wl + out) = lv;
    }

    if (lane == 0 && t == 0 && kc == 0 && blockIdx.z == 0)
        *counter = 0u;
}

// ---------------------------------------------------------------------------
// MLP fwd + u_xx (forward-mode AD). 32 points/block, 8 waves; wave owns 32
// output cols = ONE 32x32x16 MFMA tile per state. A (states) single RNE-bf16
// in LDS; B (W) hi/lo from global in fragment order, double-buffered.
// 12 MFMA/k-iter/wave (was 24 at 16x16x32): 32x32 runs the matrix pipe at
// 2495 TF vs 2075 (m119) and halves MFMA issue slots.
// REGISTER NOTE: acc = 3 x f32x16 = 48 AGPR; bh/bl dbuf 32 V; av 24 V
// -> ~104 unified regs = 4 waves/SIMD (2 blocks/CU). Do not raise the
// occupancy bound: 6 waves/EU spills the accumulators (R7 post-mortem).
// C/D layout (HW-verified m74/m101): col = lane&31,
// row = (reg&3) + 8*(reg>>2) + 4*(lane>>5).
// ---------------------------------------------------------------------------
__global__ __launch_bounds__(512, 4) void mlp_kernel(
    const float* __restrict__ x, const float* __restrict__ wq,
    const float* __restrict__ W0, const float* __restrict__ b0,
    const float* __restrict__ b1v, const float* __restrict__ b2v,
    const float* __restrict__ W3, const float* __restrict__ b3,
    const unsigned short* __restrict__ W1h, const unsigned short* __restrict__ W1l,
    const unsigned short* __restrict__ W2h, const unsigned short* __restrict__ W2l,
    float* __restrict__ u_arr, float* __restrict__ d_arr)
{
    __shared__ __align__(16) unsigned short Hb[3][MB][RS];   // 50688 B

    const int tid = threadIdx.x;
    const int gp0 = blockIdx.x * MB;

    // ---- layer 0 (1 -> 256): z'=W0[j], z''=0.  b64 LDS writes (4 cols)
    // kill the 4-way m/m+8/m+16/m+24 bank alias of scalar b16 stores.
    {
        const int m = tid & 31, seg = tid >> 5;   // 16 segs x 16 cols
        const float xm = x[gp0 + m];
        #pragma unroll
        for (int jb = 0; jb < 4; ++jb) {
            s16x4 vy, vyp, vypp;
            #pragma unroll
            for (int jl = 0; jl < 4; ++jl) {
                const int j = seg * 16 + jb * 4 + jl;
                float w = W0[j];
                float z = fmaf(xm, w, b0[j]);
                float y = fast_tanh(z);
                float s = 1.0f - y * y;
                float yp = s * w;
                float ypp = -2.0f * y * yp * w;
                vy[jl]   = (short)cvt16(y);
                vyp[jl]  = (short)cvt16(yp);
                vypp[jl] = (short)cvt16(ypp);
            }
            const int j0 = seg * 16 + jb * 4;
            *(s16x4*)&Hb[0][m][j0] = vy;
            *(s16x4*)&Hb[1][m][j0] = vyp;
            *(s16x4*)&Hb[2][m][j0] = vypp;
        }
    }
    __syncthreads();

    const int lane = tid & 63, wv = tid >> 6;      // wv 0..7
    const int c32 = lane & 31, h = lane >> 5;

    // per-wave fragment base: col tile t = wv; per (kc,ks): kc*1024 + ks*512
    const int fragbase = wv * 8192 + lane * 8;

    // ---- hidden layers 1,2 (256 -> 256)
    for (int layer = 0; layer < 2; ++layer) {
        const unsigned short* __restrict__ WhW = (layer ? W2h : W1h) + fragbase;
        const unsigned short* __restrict__ WlW = (layer ? W2l : W1l) + fragbase;
        const float* __restrict__ bb = layer ? b2v : b1v;

        f32x16 acc[3] = {};   // [state] = 48 AGPR

        s16x8 bh[2][2], bl[2][2];        // [buf][ks]
        #pragma unroll
        for (int ks = 0; ks < 2; ++ks) {
            bh[0][ks] = *(const s16x8*)(WhW + ks * 512);
            bl[0][ks] = *(const s16x8*)(WlW + ks * 512);
        }

        int cur = 0;
        for (int kc = 0; kc < 8; ++kc) {
            const int nxt = cur ^ 1;
            if (kc < 7) {
                #pragma unroll
                for (int ks = 0; ks < 2; ++ks) {
                    const int off = (kc + 1) * 1024 + ks * 512;
                    bh[nxt][ks] = *(const s16x8*)(WhW + off);
                    bl[nxt][ks] = *(const s16x8*)(WlW + off);
                }
            }
            s16x8 av[3][2];   // [state][ks]
            #pragma unroll
            for (int s = 0; s < 3; ++s)
                #pragma unroll
                for (int ks = 0; ks < 2; ++ks)
                    av[s][ks] = *(const s16x8*)&Hb[s][c32][kc * 32 + ks * 16 + h * 8];
            // hi over the 32-k chunk first, then lo (matches baseline rounding order)
            #pragma unroll
            for (int s = 0; s < 3; ++s) {
                acc[s] = __builtin_amdgcn_mfma_f32_32x32x16_bf16(
                    __builtin_bit_cast(bf16x8, av[s][0]),
                    __builtin_bit_cast(bf16x8, bh[cur][0]), acc[s], 0, 0, 0);
                acc[s] = __builtin_amdgcn_mfma_f32_32x32x16_bf16(
                    __builtin_bit_cast(bf16x8, av[s][1]),
                    __builtin_bit_cast(bf16x8, bh[cur][1]), acc[s], 0, 0, 0);
                acc[s] = __builtin_amdgcn_mfma_f32_32x32x16_bf16(
                    __builtin_bit_cast(bf16x8, av[s][0]),
                    __builtin_bit_cast(bf16x8, bl[cur][0]), acc[s], 0, 0, 0);
                acc[s] = __builtin_amdgcn_mfma_f32_32x32x16_bf16(
                    __builtin_bit_cast(bf16x8, av[s][1]),
                    __builtin_bit_cast(bf16x8, bl[cur][1]), acc[s], 0, 0, 0);
            }
            cur = nxt;
        }
        __syncthreads();   // all reads of old H done

        {
            const int c = wv * 32 + c32;
            const float bias = bb[c];
            #pragma unroll
            for (int reg = 0; reg < 16; ++reg) {
                const int r = (reg & 3) + 8 * (reg >> 2) + 4 * h;
                float z   = acc[0][reg] + bias;
                float zp  = acc[1][reg];
                float zpp = acc[2][reg];
                float y  = fast_tanh(z);
                float s  = 1.0f - y * y;
                float yp = s * zp;
                float ypp = fmaf(s, zpp, -2.0f * y * yp * zp);
                Hb[0][r][c] = cvt16(y);
                if (layer == 0) Hb[1][r][c] = cvt16(yp);  // last layer's h' never read
                Hb[2][r][c] = cvt16(ypp);
            }
        }
        __syncthreads();
    }

    // ---- final layer (256 -> 1); psum aliases Hb[1] (dead here)
    float* psum = (float*)&Hb[1][0][0];   // [2][16][32] floats = 4 KB
    {
        const int m = tid & 31, seg = tid >> 5;
        float su = 0.f, sx = 0.f;
        #pragma unroll
        for (int jj8 = 0; jj8 < 2; ++jj8) {
            const int j0 = seg * 16 + jj8 * 8;
            s16x8 vy = *(const s16x8*)&Hb[0][m][j0];
            s16x8 vx = *(const s16x8*)&Hb[2][m][j0];
            #pragma unroll
            for (int u = 0; u < 8; ++u) {
                float w3 = W3[j0 + u];
                su = fmaf(b2f((unsigned short)vy[u]), w3, su);
                sx = fmaf(b2f((unsigned short)vx[u]), w3, sx);
            }
        }
        psum[(0 * 16 + seg) * 32 + m] = su;
        psum[(1 * 16 + seg) * 32 + m] = sx;
    }
    __syncthreads();
    if (tid < MB) {
        float u = b3[0], uxx = 0.f;
        #pragma unroll
        for (int s2 = 0; s2 < 16; ++s2) {
            u   += psum[s2 * 32 + tid];
            uxx += psum[(16 + s2) * 32 + tid];
        }
        const int gp = gp0 + tid;
        u_arr[gp] = u;
        float xv = x[gp];
        d_arr[gp] = -wq[gp] * (uxx + sinpif(xv));
    }
}

// ---------------------------------------------------------------------------
// sk + fused loss. Thread owns one k for a 256-point chunk; writes partial
// sums (no init needed). sin(pi*k*x) = v_sin(fract(fma(k, xl/2, fract(k*xh/2)))):
// k*(xh/2) exact (12b x 11b mantissa), fract exact, v_sin ~ulp.
// (xh/2, xl/2, d) packed in one float4 -> 1 broadcast ds_read_b128 per
// iteration instead of 3 ds_read_b32 (loop was LDS-pipe bound).
// Last block (device-scope counter) reduces partials -> out.
// ---------------------------------------------------------------------------
__global__ __launch_bounds__(256) void sk_loss_kernel(
    const float* __restrict__ x, const float* __restrict__ d_arr,
    const float* __restrict__ u_arr, float* __restrict__ part,
    unsigned int* __restrict__ counter, float* __restrict__ out)
{
    __shared__ __align__(16) float xs4[SKC][4];
    __shared__ float red[4];
    __shared__ int lastFlag;

    const int tid = threadIdx.x;
    const int k = blockIdx.x * 256 + tid;         // 0..1023 -> k+1
    const int i0 = blockIdx.y * SKC;

    {
        float xv = x[i0 + tid];
        float xh = __uint_as_float(__float_as_uint(xv) & 0xFFFFF000u);
        f32x4 w;
        w[0] = xh * 0.5f;
        w[1] = (xv - xh) * 0.5f;
        w[2] = d_arr[i0 + tid];
        w[3] = 0.f;
        *(f32x4*)xs4[tid] = w;
    }
    __syncthreads();

    const float kf = (float)(k + 1);
    float s = 0.f;
    #pragma unroll 8
    for (int i = 0; i < SKC; ++i) {
        const f32x4 v = *(const f32x4*)xs4[i];
        float A = kf * v[0];                              // exact
        float f = __builtin_amdgcn_fractf(A);             // exact mod 1
        float t = __builtin_amdgcn_fractf(fmaf(kf, v[1], f));
        s = fmaf(__builtin_amdgcn_sinf(t), v[2], s);      // sin(2*pi*t)
    }
    part[blockIdx.y * KTEST + k] = s;

    // ---- last-block loss reduction
    __threadfence();
    if (tid == 0)
        lastFlag = (atomicAdd(counter, 1u) == (unsigned)(SKGRID - 1));
    __syncthreads();
    if (!lastFlag) return;
    __threadfence();

    float a0 = 0.f, a1 = 0.f, a2 = 0.f, a3 = 0.f;
    const float* P = part + tid * 4;
    for (int yb = 0; yb < SKYB; ++yb) {
        f32x4 v = *(const f32x4*)(P + yb * KTEST);
        a0 += v[0]; a1 += v[1]; a2 += v[2]; a3 += v[3];
    }
    float sq = a0 * a0 + a1 * a1 + a2 * a2 + a3 * a3;
    #pragma unroll
    for (int off = 32; off > 0; off >>= 1) sq += __shfl_down(sq, off, 64);
    if ((tid & 63) == 0) red[tid >> 6] = sq;
    __syncthreads();
    if (tid == 0) {
        float t = red[0] + red[1] + red[2] + red[3];
        out[0] = t * (1.0f / (float)KTEST);
        float u0 = u_arr[0], uN = u_arr[N_PTS - 1];
        out[1] = 5.0f * (u0 * u0 + uN * uN);
    }
}

extern "C" void kernel_launch(void* const* d_in, const int* in_sizes, int n_in,
                              void* d_out, int out_size, void* d_ws, size_t ws_size,
                              hipStream_t stream)
{
    const float* x  = (const float*)d_in[0];
    const float* wq = (const float*)d_in[1];
    const float* W0 = (const float*)d_in[2];
    const float* b0 = (const float*)d_in[3];
    const float* W1 = (const float*)d_in[4];
    const float* b1 = (const float*)d_in[5];
    const float* W2 = (const float*)d_in[6];
    const float* b2 = (const float*)d_in[7];
    const float* W3 = (const float*)d_in[8];
    const float* b3 = (const float*)d_in[9];
    float* out = (float*)d_out;

    float* ws    = (float*)d_ws;
    float* u_arr = ws;                       // 32768 f
    float* d_arr = ws + N_PTS;               // 32768 f
    float* part  = ws + 2 * N_PTS;           // 128*1024 f
    unsigned short* W1h = (unsigned short*)(ws + 2 * N_PTS + SKYB * KTEST);
    unsigned short* W1l = W1h + HID * HID;
    unsigned short* W2h = W1l + HID * HID;
    unsigned short* W2l = W2h + HID * HID;
    unsigned int* counter = (unsigned int*)(W2l + HID * HID);

    wswz_kernel<<<dim3(8, 8, 2), 64, 0, stream>>>(W1, W2, W1h, W1l, W2h, W2l, counter);
    mlp_kernel<<<N_PTS / MB, 512, 0, stream>>>(x, wq, W0, b0, b1, b2, W3, b3,
                                               W1h, W1l, W2h, W2l, u_arr, d_arr);
    sk_loss_kernel<<<dim3(4, SKYB), 256, 0, stream>>>(x, d_arr, u_arr, part, counter, out);
}

// Round 3
// 131.430 us; speedup vs baseline: 1.3000x; 1.3000x over previous
//
#include <hip/hip_runtime.h>
#include <cmath>

#define N_PTS 32768
#define HID   256
#define KTEST 1024
#define MB    32       // points per mlp block
#define RS    264      // padded H row stride (528 B = 33*16)
#define SKC   256      // points per sk block (fallback path)
#define SKYB  (N_PTS / SKC)     // 128
#define SKGRID (4 * SKYB)       // 512 blocks total (fallback)
#define NBLK  (N_PTS / MB)      // 1024 mlp blocks

typedef float  f32x4  __attribute__((ext_vector_type(4)));
typedef short  s16x4  __attribute__((ext_vector_type(4)));
typedef short  s16x8  __attribute__((ext_vector_type(8)));
typedef __bf16 bf16x8 __attribute__((ext_vector_type(8)));

__device__ __forceinline__ float b2f(unsigned short s) {
    return __uint_as_float(((unsigned int)s) << 16);
}
// native RNE fp32->bf16 (v_cvt_pk_bf16_f32 on gfx950)
__device__ __forceinline__ unsigned short cvt16(float x) {
    return __builtin_bit_cast(unsigned short, (__bf16)x);
}
// exact split for W: x = hi + lo_f (exact), lo = RNE16(lo_f)
__device__ __forceinline__ void split2(float x, unsigned short& hi, unsigned short& lo) {
    unsigned int b = __float_as_uint(x);
    hi = (unsigned short)(b >> 16);
    float hf = __uint_as_float(b & 0xFFFF0000u);
    lo = cvt16(x - hf);
}
__device__ __forceinline__ float fast_tanh(float z) {
    float e = __expf(2.0f * z);
    return 1.0f - 2.0f / (e + 1.0f);
}

// ---------------------------------------------------------------------------
// W[k][n] fp32 -> hi/lo bf16 in 16x16x32 MFMA B-fragment order (ROUND-0
// layout restored: 32x32x16 experiment regressed — MFMA busy went UP 17%):
//   frag(t,kc) = 64 lanes x 8 elems; lane (q=lane>>4, ln=lane&15) holds
//   W[kc*32 + q*8 + j][t*16 + ln], j=0..7.  elem offset = ((t*8+kc)*64+lane)*8
// Also zeroes the done-counter (stream-ordered before reduce/sk).
// ---------------------------------------------------------------------------
__global__ __launch_bounds__(64) void wswz_kernel(
    const float* __restrict__ W1, const float* __restrict__ W2,
    unsigned short* __restrict__ Wh1, unsigned short* __restrict__ Wl1,
    unsigned short* __restrict__ Wh2, unsigned short* __restrict__ Wl2,
    unsigned int* __restrict__ counter)
{
    const int lane = threadIdx.x;      // 0..63
    const int t  = blockIdx.x;         // col tile 0..15
    const int kc = blockIdx.y;         // k chunk 0..7
    const float* W = blockIdx.z ? W2 : W1;
    unsigned short* Wh = blockIdx.z ? Wh2 : Wh1;
    unsigned short* Wl = blockIdx.z ? Wl2 : Wl1;
    const int q = lane >> 4, ln = lane & 15;
    const int n = t * 16 + ln;
    const int kbase = kc * 32 + q * 8;

    s16x8 hv, lv;
    #pragma unroll
    for (int j = 0; j < 8; ++j) {
        unsigned short h, l;
        split2(W[(kbase + j) * HID + n], h, l);
        hv[j] = (short)h; lv[j] = (short)l;
    }
    const int out = ((t * 8 + kc) * 64 + lane) * 8;
    *(s16x8*)(Wh + out) = hv;
    *(s16x8*)(Wl + out) = lv;

    if (lane == 0 && t == 0 && kc == 0 && blockIdx.z == 0)
        *counter = 0u;
}

// ---------------------------------------------------------------------------
// MLP fwd + u_xx (forward-mode AD), 16x16x32 MFMA (round-0 structure) +
// FUSED sk partials: after the final layer each block already holds its 32
// points' d = -w*(u_xx+sin(pi x)); 512 threads then each evaluate 2 k's
// (64 sins/thread, ~1.3K wave-cyc of pure VALU/trans) and write the block's
// Rk-partial row part[b][k].  This work overlaps the co-resident block's
// MFMA phases (MfmaUtil 38% -> 62% idle to hide in) and deletes the
// sk_loss kernel + its launch gap + its x/d re-reads.
// KEPT from R1: layer-0 b64 LDS writes + final-layer b128 reads (bank
// conflicts 3.80M -> 0 measured; layer-0 scalar stores were the bulk).
// REGISTER NOTE: acc 48 AGPR + staging ~56 V = ~104 unified -> 4 waves/SIMD.
// Do not raise the occupancy bound (spills, R7 post-mortem).
// ---------------------------------------------------------------------------
__global__ __launch_bounds__(512, 4) void mlp_kernel(
    const float* __restrict__ x, const float* __restrict__ wq,
    const float* __restrict__ W0, const float* __restrict__ b0,
    const float* __restrict__ b1v, const float* __restrict__ b2v,
    const float* __restrict__ W3, const float* __restrict__ b3,
    const unsigned short* __restrict__ W1h, const unsigned short* __restrict__ W1l,
    const unsigned short* __restrict__ W2h, const unsigned short* __restrict__ W2l,
    float* __restrict__ u_arr, float* __restrict__ d_arr,
    float* __restrict__ partF)
{
    __shared__ __align__(16) unsigned short Hb[3][MB][RS];   // 50688 B
    __shared__ float sx_h[MB], sx_l[MB], sd[MB];             // +384 B

    const int tid = threadIdx.x;
    const int gp0 = blockIdx.x * MB;

    // ---- layer 0 (1 -> 256): z'=W0[j], z''=0.  b64 LDS writes (4 cols):
    // scalar b16 stores here were 4-way bank-aliased (m/m+8/m+16/m+24).
    {
        const int m = tid & 31, seg = tid >> 5;   // 16 segs x 16 cols
        const float xm = x[gp0 + m];
        #pragma unroll
        for (int jb = 0; jb < 4; ++jb) {
            s16x4 vy, vyp, vypp;
            #pragma unroll
            for (int jl = 0; jl < 4; ++jl) {
                const int j = seg * 16 + jb * 4 + jl;
                float w = W0[j];
                float z = fmaf(xm, w, b0[j]);
                float y = fast_tanh(z);
                float s = 1.0f - y * y;
                float yp = s * w;
                float ypp = -2.0f * y * yp * w;
                vy[jl]   = (short)cvt16(y);
                vyp[jl]  = (short)cvt16(yp);
                vypp[jl] = (short)cvt16(ypp);
            }
            const int j0 = seg * 16 + jb * 4;
            *(s16x4*)&Hb[0][m][j0] = vy;
            *(s16x4*)&Hb[1][m][j0] = vyp;
            *(s16x4*)&Hb[2][m][j0] = vypp;
        }
    }
    __syncthreads();

    const int lane = tid & 63, wv = tid >> 6;      // wv 0..7
    const int q = lane >> 4, ln = lane & 15;

    // per-wave fragment base: tiles (wv*2, wv*2+1); offsets nt*4096 + kc*512
    const int fragbase = (wv * 2) * 8 * 512 + lane * 8;

    // ---- hidden layers 1,2 (256 -> 256)
    for (int layer = 0; layer < 2; ++layer) {
        const unsigned short* __restrict__ WhW = (layer ? W2h : W1h) + fragbase;
        const unsigned short* __restrict__ WlW = (layer ? W2l : W1l) + fragbase;
        const float* __restrict__ bb = layer ? b2v : b1v;

        f32x4 acc[3][2][2];   // [state][mfrag][ntile] = 48 AGPR
        #pragma unroll
        for (int s = 0; s < 3; ++s)
            #pragma unroll
            for (int mf = 0; mf < 2; ++mf)
                #pragma unroll
                for (int nt = 0; nt < 2; ++nt)
                    acc[s][mf][nt] = (f32x4){0.f, 0.f, 0.f, 0.f};

        s16x8 bh[2][2], bl[2][2];
        #pragma unroll
        for (int nt = 0; nt < 2; ++nt) {
            bh[0][nt] = *(const s16x8*)(WhW + nt * 4096);
            bl[0][nt] = *(const s16x8*)(WlW + nt * 4096);
        }

        int cur = 0;
        for (int kc = 0; kc < 8; ++kc) {
            const int nxt = cur ^ 1;
            if (kc < 7) {
                #pragma unroll
                for (int nt = 0; nt < 2; ++nt) {
                    const int off = nt * 4096 + (kc + 1) * 512;
                    bh[nxt][nt] = *(const s16x8*)(WhW + off);
                    bl[nxt][nt] = *(const s16x8*)(WlW + off);
                }
            }
            s16x8 av[3][2];
            #pragma unroll
            for (int s = 0; s < 3; ++s)
                #pragma unroll
                for (int mf = 0; mf < 2; ++mf)
                    av[s][mf] = *(const s16x8*)&Hb[s][mf * 16 + ln][kc * 32 + q * 8];
            #pragma unroll
            for (int s = 0; s < 3; ++s)
                #pragma unroll
                for (int mf = 0; mf < 2; ++mf)
                    #pragma unroll
                    for (int nt = 0; nt < 2; ++nt) {
                        acc[s][mf][nt] = __builtin_amdgcn_mfma_f32_16x16x32_bf16(
                            __builtin_bit_cast(bf16x8, av[s][mf]),
                            __builtin_bit_cast(bf16x8, bh[cur][nt]), acc[s][mf][nt], 0, 0, 0);
                        acc[s][mf][nt] = __builtin_amdgcn_mfma_f32_16x16x32_bf16(
                            __builtin_bit_cast(bf16x8, av[s][mf]),
                            __builtin_bit_cast(bf16x8, bl[cur][nt]), acc[s][mf][nt], 0, 0, 0);
                    }
            cur = nxt;
        }
        __syncthreads();   // all reads of old H done

        #pragma unroll
        for (int nt = 0; nt < 2; ++nt) {
            const int c = wv * 32 + nt * 16 + ln;
            const float bias = bb[c];
            #pragma unroll
            for (int mf = 0; mf < 2; ++mf) {
                #pragma unroll
                for (int i = 0; i < 4; ++i) {
                    const int r = mf * 16 + q * 4 + i;
                    float z   = acc[0][mf][nt][i] + bias;
                    float zp  = acc[1][mf][nt][i];
                    float zpp = acc[2][mf][nt][i];
                    float y  = fast_tanh(z);
                    float s  = 1.0f - y * y;
                    float yp = s * zp;
                    float ypp = fmaf(s, zpp, -2.0f * y * yp * zp);
                    Hb[0][r][c] = cvt16(y);
                    if (layer == 0) Hb[1][r][c] = cvt16(yp);  // last layer's h' never read
                    Hb[2][r][c] = cvt16(ypp);
                }
            }
        }
        __syncthreads();
    }

    // ---- final layer (256 -> 1); psum aliases Hb[1] (dead here)
    float* psum = (float*)&Hb[1][0][0];   // [2][16][32] floats = 4 KB
    {
        const int m = tid & 31, seg = tid >> 5;
        float su = 0.f, sx = 0.f;
        #pragma unroll
        for (int jj8 = 0; jj8 < 2; ++jj8) {
            const int j0 = seg * 16 + jj8 * 8;
            s16x8 vy = *(const s16x8*)&Hb[0][m][j0];
            s16x8 vx = *(const s16x8*)&Hb[2][m][j0];
            #pragma unroll
            for (int u = 0; u < 8; ++u) {
                float w3 = W3[j0 + u];
                su = fmaf(b2f((unsigned short)vy[u]), w3, su);
                sx = fmaf(b2f((unsigned short)vx[u]), w3, sx);
            }
        }
        psum[(0 * 16 + seg) * 32 + m] = su;
        psum[(1 * 16 + seg) * 32 + m] = sx;
    }
    __syncthreads();
    if (tid < MB) {
        float u = b3[0], uxx = 0.f;
        #pragma unroll
        for (int s2 = 0; s2 < 16; ++s2) {
            u   += psum[s2 * 32 + tid];
            uxx += psum[(16 + s2) * 32 + tid];
        }
        const int gp = gp0 + tid;
        u_arr[gp] = u;
        float xv = x[gp];
        float dv = -wq[gp] * (uxx + sinpif(xv));
        d_arr[gp] = dv;
        // stash for fused sk: exact 12-bit hi split (k*xh/2 exact, k<=1024)
        float xh = __uint_as_float(__float_as_uint(xv) & 0xFFFFF000u);
        sx_h[tid] = xh * 0.5f;
        sx_l[tid] = (xv - xh) * 0.5f;
        sd[tid]   = dv;
    }

    // ---- fused sk partial: thread handles k = tid+1 and tid+513 over the
    // block's 32 points.  sin(pi*k*x) = v_sin(fract(fma(k, xl/2, fract(k*xh/2))))
    if (partF) {
        __syncthreads();
        const float k1 = (float)(tid + 1);
        const float k2 = (float)(tid + 513);
        float s1 = 0.f, s2 = 0.f;
        #pragma unroll 8
        for (int i = 0; i < MB; ++i) {
            float xh = sx_h[i], xl = sx_l[i], dv = sd[i];
            float f1 = __builtin_amdgcn_fractf(k1 * xh);           // exact
            float t1 = __builtin_amdgcn_fractf(fmaf(k1, xl, f1));
            s1 = fmaf(__builtin_amdgcn_sinf(t1), dv, s1);
            float f2 = __builtin_amdgcn_fractf(k2 * xh);
            float t2 = __builtin_amdgcn_fractf(fmaf(k2, xl, f2));
            s2 = fmaf(__builtin_amdgcn_sinf(t2), dv, s2);
        }
        partF[blockIdx.x * KTEST + tid]       = s1;   // coalesced row write
        partF[blockIdx.x * KTEST + tid + 512] = s2;
    }
}

// ---------------------------------------------------------------------------
// Column-reduce part[b][k] over b=0..1023 per k, square, mean; + boundary.
// 32 blocks x 256 thr: thread (kk=t&31, ch=t>>5) sums 128 b's for one k
// (lanes read contiguous 4B -> coalesced); LDS-combine 8 chunks/k;
// device-counter last block folds 32 block-partials + boundary loss.
// ---------------------------------------------------------------------------
__global__ __launch_bounds__(256) void reduce_kernel(
    const float* __restrict__ part, const float* __restrict__ u_arr,
    unsigned int* __restrict__ counter, float* __restrict__ red_g,
    float* __restrict__ out)
{
    __shared__ float sm[8][33];
    __shared__ int lastFlag;

    const int tid = threadIdx.x;
    const int kk = tid & 31;           // k within block
    const int ch = tid >> 5;           // b-chunk 0..7 (128 b's each)
    const int k = blockIdx.x * 32 + kk;

    const float* P = part + (ch << 7) * KTEST + k;
    float s = 0.f;
    #pragma unroll 8
    for (int b = 0; b < 128; ++b) s += P[b << 10];
    sm[ch][kk] = s;
    __syncthreads();

    if (tid < 32) {
        float t = 0.f;
        #pragma unroll
        for (int j = 0; j < 8; ++j) t += sm[j][kk];
        float sq = t * t;
        #pragma unroll
        for (int off = 16; off > 0; off >>= 1) sq += __shfl_down(sq, off, 64);
        if (kk == 0) red_g[blockIdx.x] = sq;
    }
    __threadfence();
    if (tid == 0)
        lastFlag = (atomicAdd(counter, 1u) == 31u);
    __syncthreads();
    if (!lastFlag) return;
    __threadfence();

    if (tid < 32) {
        float v = red_g[tid];
        #pragma unroll
        for (int off = 16; off > 0; off >>= 1) v += __shfl_down(v, off, 64);
        if (tid == 0) {
            out[0] = v * (1.0f / (float)KTEST);
            float u0 = u_arr[0], uN = u_arr[N_PTS - 1];
            out[1] = 5.0f * (u0 * u0 + uN * uN);
        }
    }
}

// ---------------------------------------------------------------------------
// Fallback sk + fused loss (round-0 proven version) — used only if the
// workspace can't hold the 4 MB fused partial matrix.
// ---------------------------------------------------------------------------
__global__ __launch_bounds__(256) void sk_loss_kernel(
    const float* __restrict__ x, const float* __restrict__ d_arr,
    const float* __restrict__ u_arr, float* __restrict__ part,
    unsigned int* __restrict__ counter, float* __restrict__ out)
{
    __shared__ float xs_h[SKC], xs_l[SKC], ds[SKC];
    __shared__ float red[4];
    __shared__ int lastFlag;

    const int tid = threadIdx.x;
    const int k = blockIdx.x * 256 + tid;
    const int i0 = blockIdx.y * SKC;

    {
        float xv = x[i0 + tid];
        float xh = __uint_as_float(__float_as_uint(xv) & 0xFFFFF000u);
        xs_h[tid] = xh * 0.5f;
        xs_l[tid] = (xv - xh) * 0.5f;
        ds[tid]   = d_arr[i0 + tid];
    }
    __syncthreads();

    const float kf = (float)(k + 1);
    float s = 0.f;
    #pragma unroll 8
    for (int i = 0; i < SKC; ++i) {
        float A = kf * xs_h[i];
        float f = __builtin_amdgcn_fractf(A);
        float t = __builtin_amdgcn_fractf(fmaf(kf, xs_l[i], f));
        s = fmaf(__builtin_amdgcn_sinf(t), ds[i], s);
    }
    part[blockIdx.y * KTEST + k] = s;

    __threadfence();
    if (tid == 0)
        lastFlag = (atomicAdd(counter, 1u) == (unsigned)(SKGRID - 1));
    __syncthreads();
    if (!lastFlag) return;
    __threadfence();

    float a0 = 0.f, a1 = 0.f, a2 = 0.f, a3 = 0.f;
    const float* P = part + tid * 4;
    for (int yb = 0; yb < SKYB; ++yb) {
        f32x4 v = *(const f32x4*)(P + yb * KTEST);
        a0 += v[0]; a1 += v[1]; a2 += v[2]; a3 += v[3];
    }
    float sq = a0 * a0 + a1 * a1 + a2 * a2 + a3 * a3;
    #pragma unroll
    for (int off = 32; off > 0; off >>= 1) sq += __shfl_down(sq, off, 64);
    if ((tid & 63) == 0) red[tid >> 6] = sq;
    __syncthreads();
    if (tid == 0) {
        float t = red[0] + red[1] + red[2] + red[3];
        out[0] = t * (1.0f / (float)KTEST);
        float u0 = u_arr[0], uN = u_arr[N_PTS - 1];
        out[1] = 5.0f * (u0 * u0 + uN * uN);
    }
}

extern "C" void kernel_launch(void* const* d_in, const int* in_sizes, int n_in,
                              void* d_out, int out_size, void* d_ws, size_t ws_size,
                              hipStream_t stream)
{
    const float* x  = (const float*)d_in[0];
    const float* wq = (const float*)d_in[1];
    const float* W0 = (const float*)d_in[2];
    const float* b0 = (const float*)d_in[3];
    const float* W1 = (const float*)d_in[4];
    const float* b1 = (const float*)d_in[5];
    const float* W2 = (const float*)d_in[6];
    const float* b2 = (const float*)d_in[7];
    const float* W3 = (const float*)d_in[8];
    const float* b3 = (const float*)d_in[9];
    float* out = (float*)d_out;

    float* ws    = (float*)d_ws;
    float* u_arr = ws;                       // 32768 f
    float* d_arr = ws + N_PTS;               // 32768 f
    float* partS = ws + 2 * N_PTS;           // 128*1024 f (fallback)
    unsigned short* W1h = (unsigned short*)(ws + 2 * N_PTS + SKYB * KTEST);
    unsigned short* W1l = W1h + HID * HID;
    unsigned short* W2h = W1l + HID * HID;
    unsigned short* W2l = W2h + HID * HID;
    unsigned int* counter = (unsigned int*)(W2l + HID * HID);   // f-off 327680
    float* red_g = ws + 327696;              // 32 f
    float* partF = ws + 327744;              // 1024*1024 f = 4 MB
    const size_t need = (size_t)(327744 + NBLK * KTEST) * sizeof(float);
    const bool fused = ws_size >= need;

    wswz_kernel<<<dim3(16, 8, 2), 64, 0, stream>>>(W1, W2, W1h, W1l, W2h, W2l, counter);
    mlp_kernel<<<NBLK, 512, 0, stream>>>(x, wq, W0, b0, b1, b2, W3, b3,
                                         W1h, W1l, W2h, W2l, u_arr, d_arr,
                                         fused ? partF : nullptr);
    if (fused)
        reduce_kernel<<<32, 256, 0, stream>>>(partF, u_arr, counter, red_g, out);
    else
        sk_loss_kernel<<<dim3(4, SKYB), 256, 0, stream>>>(x, d_arr, u_arr, partS, counter, out);
}